// Round 2
// baseline (225.649 us; speedup 1.0000x reference)
//
#include <hip/hip_runtime.h>

#define T_ 4096   // B*S tokens
#define D_ 1024
#define E_ 8

typedef __attribute__((ext_vector_type(8))) short short8;
typedef __attribute__((ext_vector_type(4))) float floatx4;

__device__ __forceinline__ unsigned short f2bf(float f) {
    union { float ff; unsigned int i; } v; v.ff = f;
    unsigned int i = v.i + 0x7fffu + ((v.i >> 16) & 1u);   // RNE
    return (unsigned short)(i >> 16);
}

__device__ __forceinline__ short8 pack8(float4 a, float4 b) {
    short8 r;
    r[0] = (short)f2bf(a.x); r[1] = (short)f2bf(a.y);
    r[2] = (short)f2bf(a.z); r[3] = (short)f2bf(a.w);
    r[4] = (short)f2bf(b.x); r[5] = (short)f2bf(b.y);
    r[6] = (short)f2bf(b.z); r[7] = (short)f2bf(b.w);
    return r;
}

// ---------------- Router: 1 wave per token ----------------
__global__ __launch_bounds__(256) void moe_router(
    const float* __restrict__ x,
    const float* __restrict__ rw,
    const float* __restrict__ rb,
    float* __restrict__ wts,
    int*   __restrict__ counts,
    int*   __restrict__ bucket)
{
    const int wave = threadIdx.x >> 6;
    const int lane = threadIdx.x & 63;
    const int tok  = blockIdx.x * 4 + wave;

    const float* xp = x + (size_t)tok * D_ + lane * 16;
    float xf[16];
    #pragma unroll
    for (int i = 0; i < 4; i++) {
        float4 v = *(const float4*)(xp + i * 4);
        xf[i * 4 + 0] = v.x; xf[i * 4 + 1] = v.y;
        xf[i * 4 + 2] = v.z; xf[i * 4 + 3] = v.w;
    }

    float acc[E_];
    #pragma unroll
    for (int e = 0; e < E_; e++) {
        const float* wp = rw + e * D_ + lane * 16;
        float s = 0.f;
        #pragma unroll
        for (int i = 0; i < 4; i++) {
            float4 v = *(const float4*)(wp + i * 4);
            s += xf[i * 4 + 0] * v.x + xf[i * 4 + 1] * v.y
               + xf[i * 4 + 2] * v.z + xf[i * 4 + 3] * v.w;
        }
        acc[e] = s;
    }
    // butterfly reduce all 8 logits across 64 lanes
    #pragma unroll
    for (int off = 32; off > 0; off >>= 1) {
        #pragma unroll
        for (int e = 0; e < E_; e++)
            acc[e] += __shfl_xor(acc[e], off, 64);
    }

    float lmax = -3.4e38f; int idx = 0;
    #pragma unroll
    for (int e = 0; e < E_; e++) {
        acc[e] += rb[e];
        if (acc[e] > lmax) { lmax = acc[e]; idx = e; }   // strict > = first max (numpy argmax)
    }
    float sum = 0.f;
    #pragma unroll
    for (int e = 0; e < E_; e++) sum += expf(acc[e] - lmax);

    if (lane == 0) {
        wts[tok] = 1.0f / sum;                 // softmax prob of the argmax expert
        int pos = atomicAdd(&counts[idx], 1);
        bucket[idx * T_ + pos] = tok;
    }
}

// ---------------- Grouped GEMM: 64x64 tile per block, 4 waves n-split ----------------
__global__ __launch_bounds__(256) void moe_gemm(
    const float* __restrict__ x,
    const float* __restrict__ ew,
    const float* __restrict__ eb,
    const float* __restrict__ wts,
    const int*  __restrict__ counts,
    const int*  __restrict__ bucket,
    float* __restrict__ out)
{
    const int e   = blockIdx.z;
    const int cnt = counts[e];
    const int m0  = blockIdx.y * 64;
    if (m0 >= cnt) return;                     // empty tile: fast exit
    const int n0    = blockIdx.x * 64;
    const int valid = min(64, cnt - m0);

    __shared__ int   toks[64];
    __shared__ float twt[64];
    __shared__ __align__(16) unsigned short atile[64 * 40];  // +8 pad (2-way LDS alias = free)

    const int tid = threadIdx.x;
    if (tid < 64) {
        int r = (tid < valid) ? tid : 0;       // pad rows duplicate row 0 (stores masked)
        int t = bucket[e * T_ + m0 + r];
        toks[tid] = t;
        twt[tid]  = wts[t];
    }
    __syncthreads();

    const int lane = tid & 63;
    const int w    = tid >> 6;
    const int kc   = lane >> 4;    // k-chunk 0..3 (8 bf16 each)
    const int l16  = lane & 15;

    // A staging: thread -> (row = tid/4, kchunk = tid%4), 8 f32 -> 8 bf16
    const int srow = tid >> 2;
    const int skc  = tid & 3;
    const float* xsrc = x + (size_t)toks[srow] * D_ + skc * 8;
    unsigned short* sdst = &atile[srow * 40 + skc * 8];

    const int ocol = n0 + w * 16 + l16;
    const float* bsrc = ew + ((size_t)e << 20) + (size_t)ocol * D_ + kc * 8;

    floatx4 acc[4] = {{0,0,0,0},{0,0,0,0},{0,0,0,0},{0,0,0,0}};

    for (int k0 = 0; k0 < D_; k0 += 32) {
        float4 a0 = *(const float4*)(xsrc + k0);
        float4 a1 = *(const float4*)(xsrc + k0 + 4);
        *(short8*)sdst = pack8(a0, a1);
        __syncthreads();
        float4 b0 = *(const float4*)(bsrc + k0);
        float4 b1 = *(const float4*)(bsrc + k0 + 4);
        short8 bfrag = pack8(b0, b1);          // B[k][n]: n=lane&15, k=kc*8+j
        #pragma unroll
        for (int mi = 0; mi < 4; mi++) {
            short8 afrag = *(const short8*)(&atile[(mi * 16 + l16) * 40 + kc * 8]);
            acc[mi] = __builtin_amdgcn_mfma_f32_16x16x32_bf16(afrag, bfrag, acc[mi], 0, 0, 0);
        }
        __syncthreads();
    }

    // Epilogue: C/D layout col=lane&15, row=(lane>>4)*4+reg
    const float bias = eb[e * D_ + ocol];
    const int rq = (lane >> 4) * 4;
    #pragma unroll
    for (int mi = 0; mi < 4; mi++) {
        #pragma unroll
        for (int r = 0; r < 4; r++) {
            int row = mi * 16 + rq + r;
            if (row < valid) {
                float v = (acc[mi][r] + bias) * twt[row];
                out[(size_t)toks[row] * D_ + ocol] = v;
            }
        }
    }
}

extern "C" void kernel_launch(void* const* d_in, const int* in_sizes, int n_in,
                              void* d_out, int out_size, void* d_ws, size_t ws_size,
                              hipStream_t stream) {
    (void)in_sizes; (void)n_in; (void)out_size; (void)ws_size;
    const float* x  = (const float*)d_in[0];
    const float* rw = (const float*)d_in[1];
    const float* rb = (const float*)d_in[2];
    const float* ew = (const float*)d_in[3];
    const float* eb = (const float*)d_in[4];
    float* out = (float*)d_out;

    // workspace carve: wts[T] f32 | counts[E] i32 | bucket[E][T] i32  (~148 KB)
    float* wts  = (float*)d_ws;
    int* counts = (int*)d_ws + T_;
    int* bucket = counts + E_;

    hipMemsetAsync(counts, 0, E_ * sizeof(int), stream);
    moe_router<<<dim3(T_ / 4), dim3(256), 0, stream>>>(x, rw, rb, wts, counts, bucket);
    moe_gemm<<<dim3(D_ / 64, T_ / 64, E_), dim3(256), 0, stream>>>(x, ew, eb, wts, counts, bucket, out);
}

// Round 3
// 145.820 us; speedup vs baseline: 1.5475x; 1.5475x over previous
//
#include <hip/hip_runtime.h>

#define T_ 4096   // B*S tokens
#define D_ 1024
#define E_ 8
#define MT 128
#define NT 128
#define KT 32     // k per LDS stage

typedef __attribute__((ext_vector_type(8))) short short8;
typedef __attribute__((ext_vector_type(4))) float floatx4;

__device__ __forceinline__ unsigned short f2bf(float f) {
    union { float ff; unsigned int i; } v; v.ff = f;
    unsigned int i = v.i + 0x7fffu + ((v.i >> 16) & 1u);   // RNE
    return (unsigned short)(i >> 16);
}
__device__ __forceinline__ short8 pack8(float4 a, float4 b) {
    short8 r;
    r[0] = (short)f2bf(a.x); r[1] = (short)f2bf(a.y);
    r[2] = (short)f2bf(a.z); r[3] = (short)f2bf(a.w);
    r[4] = (short)f2bf(b.x); r[5] = (short)f2bf(b.y);
    r[6] = (short)f2bf(b.z); r[7] = (short)f2bf(b.w);
    return r;
}
__device__ __forceinline__ void glds16(const void* g, void* l) {
    __builtin_amdgcn_global_load_lds(
        (const __attribute__((address_space(1))) unsigned int*)g,
        (__attribute__((address_space(3))) unsigned int*)l, 16, 0, 0);
}

// ---- Router (no atomics) + x f32->bf16 + ew f32->bf16 slice ----
__global__ __launch_bounds__(256) void moe_router(
    const float* __restrict__ x,
    const float* __restrict__ rw,
    const float* __restrict__ rb,
    const float* __restrict__ ew,
    unsigned short* __restrict__ xbf,
    unsigned short* __restrict__ ewbf,
    float* __restrict__ wts,
    int*   __restrict__ top1)
{
    const int wave = threadIdx.x >> 6;
    const int lane = threadIdx.x & 63;
    const int tok  = blockIdx.x * 4 + wave;

    const float* xp = x + (size_t)tok * D_ + lane * 16;
    float4 xv[4];
    #pragma unroll
    for (int i = 0; i < 4; i++) xv[i] = *(const float4*)(xp + i * 4);

    // write bf16 copy of x (gathered by the GEMM later)
    unsigned short* xd = xbf + (size_t)tok * D_ + lane * 16;
    *(short8*)(xd)     = pack8(xv[0], xv[1]);
    *(short8*)(xd + 8) = pack8(xv[2], xv[3]);

    float xf[16];
    #pragma unroll
    for (int i = 0; i < 4; i++) {
        xf[i*4+0] = xv[i].x; xf[i*4+1] = xv[i].y;
        xf[i*4+2] = xv[i].z; xf[i*4+3] = xv[i].w;
    }

    float acc[E_];
    #pragma unroll
    for (int e = 0; e < E_; e++) {
        const float* wp = rw + e * D_ + lane * 16;
        float s = 0.f;
        #pragma unroll
        for (int i = 0; i < 4; i++) {
            float4 v = *(const float4*)(wp + i * 4);
            s += xf[i*4+0]*v.x + xf[i*4+1]*v.y + xf[i*4+2]*v.z + xf[i*4+3]*v.w;
        }
        acc[e] = s;
    }
    #pragma unroll
    for (int off = 32; off > 0; off >>= 1) {
        #pragma unroll
        for (int e = 0; e < E_; e++)
            acc[e] += __shfl_xor(acc[e], off, 64);
    }

    float lmax = -3.4e38f; int idx = 0;
    #pragma unroll
    for (int e = 0; e < E_; e++) {
        acc[e] += rb[e];
        if (acc[e] > lmax) { lmax = acc[e]; idx = e; }   // strict > = first max (numpy argmax)
    }
    float sum = 0.f;
    #pragma unroll
    for (int e = 0; e < E_; e++) sum += expf(acc[e] - lmax);

    if (lane == 0) {
        wts[tok]  = 1.0f / sum;
        top1[tok] = idx;
    }

    // ew convert: block slice of 8192 elems (E*D*D / 1024 blocks)
    const size_t base = (size_t)blockIdx.x * 8192 + threadIdx.x * 8;
    #pragma unroll
    for (int j = 0; j < 4; j++) {
        size_t o = base + (size_t)j * 2048;
        float4 a = *(const float4*)(ew + o);
        float4 b = *(const float4*)(ew + o + 4);
        *(short8*)(ewbf + o) = pack8(a, b);
    }
}

// ---- Bucketize: single block, LDS atomics ----
__global__ __launch_bounds__(512) void moe_bucketize(
    const int* __restrict__ top1,
    int* __restrict__ counts,
    int* __restrict__ bucket)
{
    __shared__ int c[E_];
    if (threadIdx.x < E_) c[threadIdx.x] = 0;
    __syncthreads();
    for (int t = threadIdx.x; t < T_; t += 512) {
        int e = top1[t];
        int pos = atomicAdd(&c[e], 1);
        bucket[e * T_ + pos] = t;
    }
    __syncthreads();
    if (threadIdx.x < E_) counts[threadIdx.x] = c[threadIdx.x];
}

// ---- Grouped GEMM: 128x128 tile, 4 waves (2x2), global_load_lds staging ----
__global__ __launch_bounds__(256) void moe_gemm(
    const unsigned short* __restrict__ xbf,
    const unsigned short* __restrict__ ewbf,
    const float* __restrict__ eb,
    const float* __restrict__ wts,
    const int*  __restrict__ counts,
    const int*  __restrict__ bucket,
    float* __restrict__ out)
{
    const int e   = blockIdx.z;
    const int cnt = counts[e];
    const int m0  = blockIdx.y * MT;
    if (m0 >= cnt) return;
    const int n0    = blockIdx.x * NT;
    const int valid = min(MT, cnt - m0);

    __shared__ int   toks[MT];
    __shared__ float twt[MT];
    __shared__ __align__(16) unsigned short As[MT * KT];   // [row][kslot], 64B rows, XOR-swizzled
    __shared__ __align__(16) unsigned short Bs[NT * KT];   // [col][kslot]

    const int tid = threadIdx.x;
    if (tid < MT) {
        int r = (tid < valid) ? tid : 0;
        int t = bucket[e * T_ + m0 + r];
        toks[tid] = t;
        twt[tid]  = wts[t];
    }
    __syncthreads();

    const int lane = tid & 63;
    const int w    = tid >> 6;
    const int wm   = w & 1;
    const int wn   = w >> 1;

    // staging: wave w covers tile rows [w*32, w*32+32), 2 instrs of 16 rows each
    const int r0   = w * 32 + (lane >> 2);     // instr0 row; instr1 = +16
    const int r1   = r0 + 16;
    const int slot = lane & 3;
    const int gc0  = slot ^ ((r0 >> 1) & 3);   // global k-chunk held in this slot
    const int gc1  = slot ^ ((r1 >> 1) & 3);

    const unsigned short* asrc0 = xbf + (size_t)toks[r0] * D_ + gc0 * 8;
    const unsigned short* asrc1 = xbf + (size_t)toks[r1] * D_ + gc1 * 8;
    const size_t ebase = (size_t)e << 20;
    const unsigned short* bsrc0 = ewbf + ebase + (size_t)(n0 + r0) * D_ + gc0 * 8;
    const unsigned short* bsrc1 = ewbf + ebase + (size_t)(n0 + r1) * D_ + gc1 * 8;

    unsigned short* adst0 = &As[(w * 32) * KT];
    unsigned short* adst1 = &As[(w * 32 + 16) * KT];
    unsigned short* bdst0 = &Bs[(w * 32) * KT];
    unsigned short* bdst1 = &Bs[(w * 32 + 16) * KT];

    const int l16 = lane & 15;
    const int kq  = lane >> 4;

    floatx4 acc[4][4];
    #pragma unroll
    for (int i = 0; i < 4; i++)
        #pragma unroll
        for (int j = 0; j < 4; j++) acc[i][j] = (floatx4){0,0,0,0};

    for (int k0 = 0; k0 < D_; k0 += KT) {
        glds16(asrc0 + k0, adst0);
        glds16(asrc1 + k0, adst1);
        glds16(bsrc0 + k0, bdst0);
        glds16(bsrc1 + k0, bdst1);
        __syncthreads();

        short8 a[4], b[4];
        #pragma unroll
        for (int mi = 0; mi < 4; mi++) {
            int ar = wm * 64 + mi * 16 + l16;
            a[mi] = *(const short8*)&As[ar * KT + (kq ^ ((ar >> 1) & 3)) * 8];
        }
        #pragma unroll
        for (int ni = 0; ni < 4; ni++) {
            int br = wn * 64 + ni * 16 + l16;
            b[ni] = *(const short8*)&Bs[br * KT + (kq ^ ((br >> 1) & 3)) * 8];
        }
        #pragma unroll
        for (int mi = 0; mi < 4; mi++)
            #pragma unroll
            for (int ni = 0; ni < 4; ni++)
                acc[mi][ni] = __builtin_amdgcn_mfma_f32_16x16x32_bf16(a[mi], b[ni], acc[mi][ni], 0, 0, 0);
        __syncthreads();
    }

    // epilogue: C/D layout col=lane&15, row=(lane>>4)*4+reg
    const int rq = (lane >> 4) * 4;
    #pragma unroll
    for (int ni = 0; ni < 4; ni++) {
        const int col  = n0 + wn * 64 + ni * 16 + l16;
        const float bias = eb[e * D_ + col];
        #pragma unroll
        for (int mi = 0; mi < 4; mi++) {
            #pragma unroll
            for (int r = 0; r < 4; r++) {
                int row = wm * 64 + mi * 16 + rq + r;
                if (row < valid)
                    out[(size_t)toks[row] * D_ + col] = (acc[mi][ni][r] + bias) * twt[row];
            }
        }
    }
}

extern "C" void kernel_launch(void* const* d_in, const int* in_sizes, int n_in,
                              void* d_out, int out_size, void* d_ws, size_t ws_size,
                              hipStream_t stream) {
    (void)in_sizes; (void)n_in; (void)out_size; (void)ws_size;
    const float* x  = (const float*)d_in[0];
    const float* rw = (const float*)d_in[1];
    const float* rb = (const float*)d_in[2];
    const float* ew = (const float*)d_in[3];
    const float* eb = (const float*)d_in[4];
    float* out = (float*)d_out;

    // ws carve: xbf 8MB | ewbf 16MB | wts 16KB | top1 16KB | counts | bucket 128KB
    unsigned short* xbf  = (unsigned short*)d_ws;
    unsigned short* ewbf = xbf + (size_t)T_ * D_;
    float* wts  = (float*)(ewbf + (size_t)E_ * D_ * D_);
    int*   top1 = (int*)(wts + T_);
    int*   counts = top1 + T_;
    int*   bucket = counts + E_;

    moe_router<<<dim3(T_ / 4), dim3(256), 0, stream>>>(x, rw, rb, ew, xbf, ewbf, wts, top1);
    moe_bucketize<<<dim3(1), dim3(512), 0, stream>>>(top1, counts, bucket);
    moe_gemm<<<dim3(D_ / NT, T_ / MT, E_), dim3(256), 0, stream>>>(xbf, ewbf, eb, wts, counts, bucket, out);
}

// Round 4
// 126.810 us; speedup vs baseline: 1.7794x; 1.1499x over previous
//
#include <hip/hip_runtime.h>

#define T_ 4096   // B*S tokens
#define D_ 1024
#define E_ 8
#define MT 64
#define NT 128
#define KT 32     // k per LDS stage

typedef __attribute__((ext_vector_type(8))) short short8;
typedef __attribute__((ext_vector_type(4))) float floatx4;

__device__ __forceinline__ unsigned short f2bf(float f) {
    union { float ff; unsigned int i; } v; v.ff = f;
    unsigned int i = v.i + 0x7fffu + ((v.i >> 16) & 1u);   // RNE
    return (unsigned short)(i >> 16);
}
__device__ __forceinline__ short8 pack8(float4 a, float4 b) {
    short8 r;
    r[0] = (short)f2bf(a.x); r[1] = (short)f2bf(a.y);
    r[2] = (short)f2bf(a.z); r[3] = (short)f2bf(a.w);
    r[4] = (short)f2bf(b.x); r[5] = (short)f2bf(b.y);
    r[6] = (short)f2bf(b.z); r[7] = (short)f2bf(b.w);
    return r;
}
__device__ __forceinline__ void glds16(const void* g, void* l) {
    __builtin_amdgcn_global_load_lds(
        (const __attribute__((address_space(1))) unsigned int*)g,
        (__attribute__((address_space(3))) unsigned int*)l, 16, 0, 0);
}

// ---- Router (no atomics) + x f32->bf16 + ew f32->bf16 slice ----
__global__ __launch_bounds__(256) void moe_router(
    const float* __restrict__ x,
    const float* __restrict__ rw,
    const float* __restrict__ rb,
    const float* __restrict__ ew,
    unsigned short* __restrict__ xbf,
    unsigned short* __restrict__ ewbf,
    float* __restrict__ wts,
    int*   __restrict__ top1)
{
    const int wave = threadIdx.x >> 6;
    const int lane = threadIdx.x & 63;
    const int tok  = blockIdx.x * 4 + wave;

    const float* xp = x + (size_t)tok * D_ + lane * 16;
    float4 xv[4];
    #pragma unroll
    for (int i = 0; i < 4; i++) xv[i] = *(const float4*)(xp + i * 4);

    unsigned short* xd = xbf + (size_t)tok * D_ + lane * 16;
    *(short8*)(xd)     = pack8(xv[0], xv[1]);
    *(short8*)(xd + 8) = pack8(xv[2], xv[3]);

    float xf[16];
    #pragma unroll
    for (int i = 0; i < 4; i++) {
        xf[i*4+0] = xv[i].x; xf[i*4+1] = xv[i].y;
        xf[i*4+2] = xv[i].z; xf[i*4+3] = xv[i].w;
    }

    float acc[E_];
    #pragma unroll
    for (int e = 0; e < E_; e++) {
        const float* wp = rw + e * D_ + lane * 16;
        float s = 0.f;
        #pragma unroll
        for (int i = 0; i < 4; i++) {
            float4 v = *(const float4*)(wp + i * 4);
            s += xf[i*4+0]*v.x + xf[i*4+1]*v.y + xf[i*4+2]*v.z + xf[i*4+3]*v.w;
        }
        acc[e] = s;
    }
    #pragma unroll
    for (int off = 32; off > 0; off >>= 1) {
        #pragma unroll
        for (int e = 0; e < E_; e++)
            acc[e] += __shfl_xor(acc[e], off, 64);
    }

    float lmax = -3.4e38f; int idx = 0;
    #pragma unroll
    for (int e = 0; e < E_; e++) {
        acc[e] += rb[e];
        if (acc[e] > lmax) { lmax = acc[e]; idx = e; }   // strict > = first max (numpy argmax)
    }
    float sum = 0.f;
    #pragma unroll
    for (int e = 0; e < E_; e++) sum += expf(acc[e] - lmax);

    if (lane == 0) {
        wts[tok]  = 1.0f / sum;
        top1[tok] = idx;
    }

    // ew convert: block slice of 8192 elems
    const size_t base = (size_t)blockIdx.x * 8192 + threadIdx.x * 8;
    #pragma unroll
    for (int j = 0; j < 4; j++) {
        size_t o = base + (size_t)j * 2048;
        float4 a = *(const float4*)(ew + o);
        float4 b = *(const float4*)(ew + o + 4);
        *(short8*)(ewbf + o) = pack8(a, b);
    }
}

// ---- Bucketize: single block, LDS atomics ----
__global__ __launch_bounds__(512) void moe_bucketize(
    const int* __restrict__ top1,
    int* __restrict__ counts,
    int* __restrict__ bucket)
{
    __shared__ int c[E_];
    if (threadIdx.x < E_) c[threadIdx.x] = 0;
    __syncthreads();
    for (int t = threadIdx.x; t < T_; t += 512) {
        int e = top1[t];
        int pos = atomicAdd(&c[e], 1);
        bucket[e * T_ + pos] = t;
    }
    __syncthreads();
    if (threadIdx.x < E_) counts[threadIdx.x] = c[threadIdx.x];
}

// ---- Grouped GEMM: 64x128 tile, 2 blocks/CU, expert->XCD pinned ----
__global__ __launch_bounds__(256) void moe_gemm(
    const unsigned short* __restrict__ xbf,
    const unsigned short* __restrict__ ewbf,
    const float* __restrict__ eb,
    const float* __restrict__ wts,
    const int*  __restrict__ counts,
    const int*  __restrict__ bucket,
    float* __restrict__ out)
{
    const int bid = blockIdx.x;
    const int e   = bid & 7;            // consecutive bids -> different experts -> XCD RR pins expert to XCD
    const int nb  = (bid >> 3) & 7;
    const int mt  = bid >> 6;           // 0..31
    const int cnt = counts[e];
    if (mt * MT >= cnt) return;
    const int n0 = nb * NT;

    __shared__ int   toks[MT];
    __shared__ float twt[MT];
    __shared__ __align__(16) unsigned short Stage[(MT + NT) * KT];  // rows 0-63 = A, 64-191 = B cols

    const int tid  = threadIdx.x;
    const int lane = tid & 63;
    const int w    = tid >> 6;
    const int wm   = w >> 1;            // 0/1: rows wm*32
    const int wn   = w & 1;             // 0/1: cols wn*64
    const int l16  = lane & 15;
    const int kq   = lane >> 4;         // 0..3

    // staging: 12 glds16 per stage, 3 per wave; instr j covers stage rows 16j..16j+15
    int srow[3]; int sgc[3]; unsigned short* sdst[3];
    #pragma unroll
    for (int i = 0; i < 3; i++) {
        int j   = w * 3 + i;
        int row = j * 16 + (lane >> 2);
        int slot = lane & 3;
        srow[i] = row;
        sgc[i]  = slot ^ ((row >> 1) & 3);   // XOR swizzle: global k-chunk stored in this slot
        sdst[i] = &Stage[j * 512];           // + lane*16B implicit in glds
    }
    const size_t ebase = (size_t)e << 20;

    for (int m0 = mt * MT; m0 < cnt; m0 += 32 * MT) {
        const int valid = min(MT, cnt - m0);
        __syncthreads();                     // protect toks/twt across m0 iterations
        if (tid < MT) {
            int r = (tid < valid) ? tid : 0;
            int t = bucket[e * T_ + m0 + r];
            toks[tid] = t;
            twt[tid]  = wts[t];
        }
        __syncthreads();

        const unsigned short* src[3];
        #pragma unroll
        for (int i = 0; i < 3; i++) {
            int row = srow[i];
            src[i] = (row < MT)
                ? xbf + (size_t)toks[row] * D_ + sgc[i] * 8
                : ewbf + ebase + (size_t)(n0 + row - MT) * D_ + sgc[i] * 8;
        }

        floatx4 acc[2][4];
        #pragma unroll
        for (int mi = 0; mi < 2; mi++)
            #pragma unroll
            for (int ni = 0; ni < 4; ni++) acc[mi][ni] = (floatx4){0,0,0,0};

        for (int k0 = 0; k0 < D_; k0 += KT) {
            #pragma unroll
            for (int i = 0; i < 3; i++) glds16(src[i] + k0, sdst[i]);
            __syncthreads();

            short8 a[2], b[4];
            #pragma unroll
            for (int mi = 0; mi < 2; mi++) {
                int ar = wm * 32 + mi * 16 + l16;
                a[mi] = *(const short8*)&Stage[ar * KT + (kq ^ ((ar >> 1) & 3)) * 8];
            }
            #pragma unroll
            for (int ni = 0; ni < 4; ni++) {
                int br = MT + wn * 64 + ni * 16 + l16;
                b[ni] = *(const short8*)&Stage[br * KT + (kq ^ ((br >> 1) & 3)) * 8];
            }
            __syncthreads();
            #pragma unroll
            for (int mi = 0; mi < 2; mi++)
                #pragma unroll
                for (int ni = 0; ni < 4; ni++)
                    acc[mi][ni] = __builtin_amdgcn_mfma_f32_16x16x32_bf16(a[mi], b[ni], acc[mi][ni], 0, 0, 0);
        }

        // epilogue: C/D layout col=lane&15, row=(lane>>4)*4+reg
        const int rq = kq * 4;
        #pragma unroll
        for (int ni = 0; ni < 4; ni++) {
            const int col  = n0 + wn * 64 + ni * 16 + l16;
            const float bias = eb[e * D_ + col];
            #pragma unroll
            for (int mi = 0; mi < 2; mi++) {
                #pragma unroll
                for (int r = 0; r < 4; r++) {
                    int row = wm * 32 + mi * 16 + rq + r;
                    if (row < valid)
                        out[(size_t)toks[row] * D_ + col] = (acc[mi][ni][r] + bias) * twt[row];
                }
            }
        }
    }
}

extern "C" void kernel_launch(void* const* d_in, const int* in_sizes, int n_in,
                              void* d_out, int out_size, void* d_ws, size_t ws_size,
                              hipStream_t stream) {
    (void)in_sizes; (void)n_in; (void)out_size; (void)ws_size;
    const float* x  = (const float*)d_in[0];
    const float* rw = (const float*)d_in[1];
    const float* rb = (const float*)d_in[2];
    const float* ew = (const float*)d_in[3];
    const float* eb = (const float*)d_in[4];
    float* out = (float*)d_out;

    // ws carve: xbf 8MB | ewbf 16MB | wts | top1 | counts | bucket
    unsigned short* xbf  = (unsigned short*)d_ws;
    unsigned short* ewbf = xbf + (size_t)T_ * D_;
    float* wts    = (float*)(ewbf + (size_t)E_ * D_ * D_);
    int*   top1   = (int*)(wts + T_);
    int*   counts = top1 + T_;
    int*   bucket = counts + E_;

    moe_router<<<dim3(T_ / 4), dim3(256), 0, stream>>>(x, rw, rb, ew, xbf, ewbf, wts, top1);
    moe_bucketize<<<dim3(1), dim3(512), 0, stream>>>(top1, counts, bucket);
    moe_gemm<<<dim3(2048), dim3(256), 0, stream>>>(xbf, ewbf, eb, wts, counts, bucket, out);
}